// Round 1
// baseline (596.759 us; speedup 1.0000x reference)
//
#include <hip/hip_runtime.h>
#include <hip/hip_bf16.h>
#include <stdint.h>

#define NN 100000
#define NE 50000
#define DIM 128

using bf16x8 = __attribute__((ext_vector_type(8))) short;
using f32x4  = __attribute__((ext_vector_type(4))) float;

__device__ inline short f2bf(float f) {
  union { float f; unsigned u; } x; x.f = f;
  unsigned u = x.u;
  unsigned r = (u + 0x7FFFu + ((u >> 16) & 1u)) >> 16;
  return (short)r;
}

__global__ void count_kernel(const int* __restrict__ nidx, const int* __restrict__ eidx,
                             int ni, int* __restrict__ ncnt, int* __restrict__ ecnt) {
  int i = blockIdx.x * blockDim.x + threadIdx.x;
  int stride = gridDim.x * blockDim.x;
  for (; i < ni; i += stride) {
    atomicAdd(&ncnt[nidx[i]], 1);
    atomicAdd(&ecnt[eidx[i]], 1);
  }
}

__global__ void scan_pass1(const int* __restrict__ in, int n, int* __restrict__ part) {
  __shared__ int sh[256];
  int base = blockIdx.x * 1024;
  int s = 0;
  for (int j = threadIdx.x; j < 1024; j += 256) {
    int idx = base + j;
    if (idx < n) s += in[idx];
  }
  sh[threadIdx.x] = s; __syncthreads();
  for (int o = 128; o > 0; o >>= 1) {
    if (threadIdx.x < o) sh[threadIdx.x] += sh[threadIdx.x + o];
    __syncthreads();
  }
  if (threadIdx.x == 0) part[blockIdx.x] = sh[0];
}

__global__ void scan_pass2(int* __restrict__ part, int nb) {
  __shared__ int sh[256];
  int t = threadIdx.x;
  sh[t] = (t < nb) ? part[t] : 0;
  __syncthreads();
  for (int o = 1; o < 256; o <<= 1) {
    int v = (t >= o) ? sh[t - o] : 0;
    __syncthreads();
    sh[t] += v;
    __syncthreads();
  }
  if (t < nb) part[t] = (t > 0) ? sh[t - 1] : 0;
}

__global__ void scan_pass3(const int* __restrict__ in, int n, const int* __restrict__ part,
                           int* __restrict__ off, int total) {
  __shared__ int sh[256];
  int t = threadIdx.x;
  int base = blockIdx.x * 1024 + t * 4;
  int v0 = 0, v1 = 0, v2 = 0, v3 = 0;
  if (base + 0 < n) v0 = in[base + 0];
  if (base + 1 < n) v1 = in[base + 1];
  if (base + 2 < n) v2 = in[base + 2];
  if (base + 3 < n) v3 = in[base + 3];
  int tsum = v0 + v1 + v2 + v3;
  sh[t] = tsum; __syncthreads();
  for (int o = 1; o < 256; o <<= 1) {
    int v = (t >= o) ? sh[t - o] : 0;
    __syncthreads();
    sh[t] += v;
    __syncthreads();
  }
  int excl = (t > 0) ? sh[t - 1] : 0;
  int b = part[blockIdx.x] + excl;
  if (base + 0 < n) off[base + 0] = b;
  if (base + 1 < n) off[base + 1] = b + v0;
  if (base + 2 < n) off[base + 2] = b + v0 + v1;
  if (base + 3 < n) off[base + 3] = b + v0 + v1 + v2;
  if (blockIdx.x == 0 && t == 0) off[n] = total;
}

__global__ void fill_kernel(const int* __restrict__ nidx, const int* __restrict__ eidx, int ni,
                            const int* __restrict__ noff, const int* __restrict__ eoff,
                            int* __restrict__ ncnt, int* __restrict__ ecnt,
                            int* __restrict__ node_edges, int* __restrict__ edge_nodes) {
  int i = blockIdx.x * blockDim.x + threadIdx.x;
  int stride = gridDim.x * blockDim.x;
  for (; i < ni; i += stride) {
    int nd = nidx[i], ed = eidx[i];
    int pe = atomicAdd(&ecnt[ed], 1);
    edge_nodes[eoff[ed] + pe] = nd;
    int pn = atomicAdd(&ncnt[nd], 1);
    node_edges[noff[nd] + pn] = ed;
  }
}

__global__ void inv_kernel(const int* __restrict__ ncnt, const int* __restrict__ ecnt,
                           float* __restrict__ ninv, float* __restrict__ einv) {
  int i = blockIdx.x * blockDim.x + threadIdx.x;
  if (i < NN) { int c = ncnt[i]; ninv[i] = (c > 0) ? 1.0f / (float)c : 0.0f; }
  if (i < NE) { int c = ecnt[i]; einv[i] = (c > 0) ? 1.0f / (float)c : 0.0f; }
}

// Pack weight [128][128] f32 into MFMA B-fragment order (bf16):
// wp[w][((ct*4+kk)*64 + lane)*8 + j] = W[kk*32 + (lane>>4)*8 + j][ct*16 + (lane&15)]
__global__ void packw_kernel(const float* __restrict__ w0, const float* __restrict__ w1,
                             const float* __restrict__ w2, const float* __restrict__ w3,
                             short* __restrict__ wp) {
  int gid = blockIdx.x * blockDim.x + threadIdx.x;
  if (gid >= 4 * 16384) return;
  int w = gid >> 14, r = gid & 16383;
  int j = r & 7, lane = (r >> 3) & 63, kk = (r >> 9) & 3, ct = (r >> 11) & 7;
  int k = kk * 32 + (lane >> 4) * 8 + j;
  int c = ct * 16 + (lane & 15);
  const float* W = (w == 0) ? w0 : (w == 1) ? w1 : (w == 2) ? w2 : w3;
  wp[gid] = f2bf(W[k * 128 + c]);
}

// C[M,128] = A[M,128] @ W[128,128], A f32 (converted to bf16 in-reg), W pre-packed bf16.
__global__ __launch_bounds__(256) void gemm_kernel(const float* __restrict__ A,
                                                   const short* __restrict__ Wp,
                                                   float* __restrict__ C, int M) {
  int wave = threadIdx.x >> 6;
  int lane = threadIdx.x & 63;
  int rt = blockIdx.x * 4 + wave;
  if (rt * 16 >= M) return;
  int kg = lane >> 4;
  int rloc = lane & 15;
  const float* arow = A + (size_t)(rt * 16 + rloc) * 128 + kg * 8;
  bf16x8 a[4];
#pragma unroll
  for (int kk = 0; kk < 4; kk++) {
    float4 lo = *(const float4*)(arow + kk * 32);
    float4 hi = *(const float4*)(arow + kk * 32 + 4);
    bf16x8 t;
    t[0] = f2bf(lo.x); t[1] = f2bf(lo.y); t[2] = f2bf(lo.z); t[3] = f2bf(lo.w);
    t[4] = f2bf(hi.x); t[5] = f2bf(hi.y); t[6] = f2bf(hi.z); t[7] = f2bf(hi.w);
    a[kk] = t;
  }
#pragma unroll
  for (int ct = 0; ct < 8; ct++) {
    f32x4 acc = {0.f, 0.f, 0.f, 0.f};
#pragma unroll
    for (int kk = 0; kk < 4; kk++) {
      bf16x8 b = *(const bf16x8*)(Wp + ((size_t)(ct * 4 + kk) * 64 + lane) * 8);
      acc = __builtin_amdgcn_mfma_f32_16x16x32_bf16(a[kk], b, acc, 0, 0, 0);
    }
    size_t cbase = (size_t)(rt * 16 + kg * 4) * 128 + ct * 16 + rloc;
#pragma unroll
    for (int j = 0; j < 4; j++) C[cbase + (size_t)j * 128] = acc[j];
  }
}

// dst[t][:] = prelu( inv[t] * sum_{i in csr(t)} src[ids[i]][:] + bias, alpha )
__global__ __launch_bounds__(256) void gather_kernel(const float4* __restrict__ src,
                                                     float4* __restrict__ dst,
                                                     const int* __restrict__ off,
                                                     const int* __restrict__ ids,
                                                     const float* __restrict__ inv,
                                                     const float* __restrict__ bias,
                                                     const float* __restrict__ alpha_p,
                                                     int T) {
  int tgt = blockIdx.x * 8 + (threadIdx.x >> 5);
  if (tgt >= T) return;
  int c4 = threadIdx.x & 31;
  int s = off[tgt], e = off[tgt + 1];
  float sx = 0.f, sy = 0.f, sz = 0.f, sw = 0.f;
  for (int i = s; i < e; i++) {
    int sid = ids[i];
    float4 v = src[(size_t)sid * 32 + c4];
    sx += v.x; sy += v.y; sz += v.z; sw += v.w;
  }
  float sc = inv[tgt];
  float a = *alpha_p;
  float bx = 0.f, by = 0.f, bz = 0.f, bw = 0.f;
  if (bias) {
    float4 b = ((const float4*)bias)[c4];
    bx = b.x; by = b.y; bz = b.z; bw = b.w;
  }
  float rx = sx * sc + bx; rx = (rx >= 0.f) ? rx : a * rx;
  float ry = sy * sc + by; ry = (ry >= 0.f) ? ry : a * ry;
  float rz = sz * sc + bz; rz = (rz >= 0.f) ? rz : a * rz;
  float rw = sw * sc + bw; rw = (rw >= 0.f) ? rw : a * rw;
  float4 r; r.x = rx; r.y = ry; r.z = rz; r.w = rw;
  dst[(size_t)tgt * 32 + c4] = r;
}

extern "C" void kernel_launch(void* const* d_in, const int* in_sizes, int n_in,
                              void* d_out, int out_size, void* d_ws, size_t ws_size,
                              hipStream_t stream) {
  const float* x = (const float*)d_in[0];
  const int* nidx = (const int*)d_in[1];
  int NI = in_sizes[1] / 2;
  const int* eidx = nidx + NI;
  const float* W0 = (const float*)d_in[2];
  const float* W1 = (const float*)d_in[3];
  const float* b0 = (const float*)d_in[4];
  const float* W2 = (const float*)d_in[5];
  const float* W3 = (const float*)d_in[6];
  const float* b1 = (const float*)d_in[7];
  const float* alpha = (const float*)d_in[8];

  char* ws = (char*)d_ws;
  size_t o = 0;
  auto alloc = [&](size_t bytes) { void* p = ws + o; o += (bytes + 255) & ~255ull; return p; };
  int* ncnt = (int*)alloc((size_t)NN * 4);
  int* ecnt = (int*)alloc((size_t)NE * 4);
  int* noff = (int*)alloc((size_t)(NN + 1) * 4);
  int* eoff = (int*)alloc((size_t)(NE + 1) * 4);
  int* part = (int*)alloc(256 * 4);
  int* node_edges = (int*)alloc((size_t)NI * 4);
  int* edge_nodes = (int*)alloc((size_t)NI * 4);
  float* ninv = (float*)alloc((size_t)NN * 4);
  float* einv = (float*)alloc((size_t)NE * 4);
  short* wp = (short*)alloc((size_t)4 * 16384 * 2);
  float* bufA = (float*)alloc((size_t)NN * 128 * 4);
  float* bufC = (float*)alloc((size_t)NE * 128 * 4);

  float* outN = (float*)d_out;
  float* outE = outN + (size_t)NN * 128;

  hipMemsetAsync(ncnt, 0, (size_t)NN * 4, stream);
  hipMemsetAsync(ecnt, 0, (size_t)NE * 4, stream);
  count_kernel<<<2048, 256, 0, stream>>>(nidx, eidx, NI, ncnt, ecnt);

  int nbN = (NN + 1023) / 1024;
  int nbE = (NE + 1023) / 1024;
  scan_pass1<<<nbE, 256, 0, stream>>>(ecnt, NE, part);
  scan_pass2<<<1, 256, 0, stream>>>(part, nbE);
  scan_pass3<<<nbE, 256, 0, stream>>>(ecnt, NE, part, eoff, NI);
  scan_pass1<<<nbN, 256, 0, stream>>>(ncnt, NN, part);
  scan_pass2<<<1, 256, 0, stream>>>(part, nbN);
  scan_pass3<<<nbN, 256, 0, stream>>>(ncnt, NN, part, noff, NI);

  hipMemsetAsync(ncnt, 0, (size_t)NN * 4, stream);
  hipMemsetAsync(ecnt, 0, (size_t)NE * 4, stream);
  fill_kernel<<<2048, 256, 0, stream>>>(nidx, eidx, NI, noff, eoff, ncnt, ecnt,
                                        node_edges, edge_nodes);
  inv_kernel<<<(NN + 255) / 256, 256, 0, stream>>>(ncnt, ecnt, ninv, einv);
  packw_kernel<<<(4 * 16384 + 255) / 256, 256, 0, stream>>>(W0, W1, W2, W3, wp);

  // layer 0
  gemm_kernel<<<(NN / 16 + 3) / 4, 256, 0, stream>>>(x, wp + 0 * 16384, bufA, NN);
  gather_kernel<<<(NE + 7) / 8, 256, 0, stream>>>((const float4*)bufA, (float4*)outE,
                                                  eoff, edge_nodes, einv, nullptr, alpha, NE);
  gemm_kernel<<<(NE / 16 + 3) / 4, 256, 0, stream>>>(outE, wp + 1 * 16384, bufC, NE);
  gather_kernel<<<(NN + 7) / 8, 256, 0, stream>>>((const float4*)bufC, (float4*)outN,
                                                  noff, node_edges, ninv, b0, alpha, NN);
  // layer 1
  gemm_kernel<<<(NN / 16 + 3) / 4, 256, 0, stream>>>(outN, wp + 2 * 16384, bufA, NN);
  gather_kernel<<<(NE + 7) / 8, 256, 0, stream>>>((const float4*)bufA, (float4*)outE,
                                                  eoff, edge_nodes, einv, nullptr, alpha, NE);
  gemm_kernel<<<(NE / 16 + 3) / 4, 256, 0, stream>>>(outE, wp + 3 * 16384, bufC, NE);
  gather_kernel<<<(NN + 7) / 8, 256, 0, stream>>>((const float4*)bufC, (float4*)outN,
                                                  noff, node_edges, ninv, b1, alpha, NN);
}

// Round 2
// 320.969 us; speedup vs baseline: 1.8592x; 1.8592x over previous
//
#include <hip/hip_runtime.h>
#include <stdint.h>

#define NN 100000
#define NE 50000
#define NBLK 256   // blocks in binning phases
#define NBK 196    // buckets (both orientations)
#define ESH 8      // edge bucket shift: 256 edge targets / bucket  -> ceil(50000/256)=196
#define NSH 9      // node bucket shift: 512 node targets / bucket  -> ceil(100000/512)=196

using bf16x8 = __attribute__((ext_vector_type(8))) short;
using f32x4  = __attribute__((ext_vector_type(4))) float;

__device__ inline unsigned f2bf(float f) {
  union { float f; unsigned u; } x; x.f = f;
  unsigned u = x.u;
  return (u + 0x7FFFu + ((u >> 16) & 1u)) >> 16;  // RNE, low 16 bits valid
}
__device__ inline float bfbits2f(unsigned bits) {  // bits already in high-half position
  union { unsigned u; float f; } x; x.u = bits;
  return x.f;
}

// ---------------- CSR build: two-level counting sort, both orientations ----------------

__global__ __launch_bounds__(256) void hist_kernel(const int* __restrict__ nidx,
                                                   const int* __restrict__ eidx, int ni,
                                                   int* __restrict__ He, int* __restrict__ Hn) {
  __shared__ int he[NBK], hn[NBK];
  for (int t = threadIdx.x; t < NBK; t += 256) { he[t] = 0; hn[t] = 0; }
  __syncthreads();
  int chunk = (ni + NBLK - 1) / NBLK;
  int s = blockIdx.x * chunk, e = min(s + chunk, ni);
  for (int i = s + threadIdx.x; i < e; i += 256) {
    atomicAdd(&he[eidx[i] >> ESH], 1);
    atomicAdd(&hn[nidx[i] >> NSH], 1);
  }
  __syncthreads();
  for (int t = threadIdx.x; t < NBK; t += 256) {
    He[t * NBLK + blockIdx.x] = he[t];
    Hn[t * NBLK + blockIdx.x] = hn[t];
  }
}

// grid=2: block0 scans He -> ebb, block1 scans Hn -> nbb. Rewrites H to global bases.
__global__ __launch_bounds__(256) void scanH_kernel(int* __restrict__ He, int* __restrict__ Hn,
                                                    int* __restrict__ ebb, int* __restrict__ nbb,
                                                    int ni) {
  int* H = blockIdx.x ? Hn : He;
  int* bb = blockIdx.x ? nbb : ebb;
  __shared__ int tot[256];
  int t = threadIdx.x;
  int sum = 0;
  if (t < NBK)
    for (int b = 0; b < NBLK; b++) sum += H[t * NBLK + b];
  tot[t] = sum;
  __syncthreads();
  for (int o = 1; o < 256; o <<= 1) {
    int v = (t >= o) ? tot[t - o] : 0;
    __syncthreads();
    tot[t] += v;
    __syncthreads();
  }
  int base = (t > 0) ? tot[t - 1] : 0;
  if (t < NBK) {
    bb[t] = base;
    int run = base;
    for (int b = 0; b < NBLK; b++) {
      int old = H[t * NBLK + b];
      H[t * NBLK + b] = run;
      run += old;
    }
  }
  if (t == 0) bb[NBK] = ni;
}

__global__ __launch_bounds__(256) void scatter_kernel(const int* __restrict__ nidx,
                                                      const int* __restrict__ eidx, int ni,
                                                      const int* __restrict__ He,
                                                      const int* __restrict__ Hn,
                                                      int2* __restrict__ binE,
                                                      int2* __restrict__ binN) {
  __shared__ int ce[NBK], cn[NBK];
  for (int t = threadIdx.x; t < NBK; t += 256) {
    ce[t] = He[t * NBLK + blockIdx.x];
    cn[t] = Hn[t * NBLK + blockIdx.x];
  }
  __syncthreads();
  int chunk = (ni + NBLK - 1) / NBLK;
  int s = blockIdx.x * chunk, e = min(s + chunk, ni);
  for (int i = s + threadIdx.x; i < e; i += 256) {
    int nd = nidx[i], ed = eidx[i];
    int pe = atomicAdd(&ce[ed >> ESH], 1);
    binE[pe] = make_int2(nd, ed);
    int pn = atomicAdd(&cn[nd >> NSH], 1);
    binN[pn] = make_int2(ed, nd);
  }
}

// grid = 2*NBK: blocks [0,NBK) finalize edge CSR, [NBK,2*NBK) node CSR.
__global__ __launch_bounds__(256) void finalize_kernel(const int2* __restrict__ binE,
                                                       const int2* __restrict__ binN,
                                                       const int* __restrict__ ebb,
                                                       const int* __restrict__ nbb,
                                                       int* __restrict__ eoff, int* __restrict__ noff,
                                                       float* __restrict__ einv, float* __restrict__ ninv,
                                                       int* __restrict__ edge_nodes,
                                                       int* __restrict__ node_edges, int ni) {
  __shared__ int cnt[512], excl[512], sc[256];
  bool isE = blockIdx.x < NBK;
  int b = isE ? blockIdx.x : blockIdx.x - NBK;
  const int2* bin = isE ? binE : binN;
  const int* bb = isE ? ebb : nbb;
  int* off = isE ? eoff : noff;
  float* inv = isE ? einv : ninv;
  int* out = isE ? edge_nodes : node_edges;
  int NT = isE ? NE : NN;
  int sh = isE ? ESH : NSH;
  int tbase = b << sh;
  int nt = min(1 << sh, NT - tbase);
  int t = threadIdx.x;
  cnt[t] = 0; cnt[t + 256] = 0;
  __syncthreads();
  int s = bb[b], e = bb[b + 1];
  for (int i = s + t; i < e; i += 256) atomicAdd(&cnt[bin[i].y - tbase], 1);
  __syncthreads();
  int p = cnt[2 * t] + cnt[2 * t + 1];
  sc[t] = p;
  __syncthreads();
  for (int o = 1; o < 256; o <<= 1) {
    int v = (t >= o) ? sc[t - o] : 0;
    __syncthreads();
    sc[t] += v;
    __syncthreads();
  }
  int pb = (t > 0) ? sc[t - 1] : 0;
  excl[2 * t] = pb;
  excl[2 * t + 1] = pb + cnt[2 * t];
  __syncthreads();
  for (int lt = t; lt < nt; lt += 256) {
    off[tbase + lt] = s + excl[lt];
    int c = cnt[lt];
    inv[tbase + lt] = (c > 0) ? 1.0f / (float)c : 0.0f;
  }
  if (b == NBK - 1 && t == 0) off[NT] = ni;
  __syncthreads();
  cnt[t] = 0; cnt[t + 256] = 0;
  __syncthreads();
  for (int i = s + t; i < e; i += 256) {
    int2 it = bin[i];
    int lt = it.y - tbase;
    int pos = s + excl[lt] + atomicAdd(&cnt[lt], 1);
    out[pos] = it.x;
  }
}

// ---------------- weights pack (bf16 MFMA B-fragment order) ----------------
__global__ void packw_kernel(const float* __restrict__ w0, const float* __restrict__ w1,
                             const float* __restrict__ w2, const float* __restrict__ w3,
                             short* __restrict__ wp) {
  int gid = blockIdx.x * blockDim.x + threadIdx.x;
  if (gid >= 4 * 16384) return;
  int w = gid >> 14, r = gid & 16383;
  int j = r & 7, lane = (r >> 3) & 63, kk = (r >> 9) & 3, ct = (r >> 11) & 7;
  int k = kk * 32 + (lane >> 4) * 8 + j;
  int c = ct * 16 + (lane & 15);
  const float* W = (w == 0) ? w0 : (w == 1) ? w1 : (w == 2) ? w2 : w3;
  wp[gid] = (short)f2bf(W[k * 128 + c]);
}

// ---------------- GEMM: C[M,128] = A[M,128] @ W(packed), A f32 or bf16, C bf16 ----------------
template <bool ABF>
__global__ __launch_bounds__(256) void gemm_kernel(const void* __restrict__ Ap,
                                                   const short* __restrict__ Wp,
                                                   short* __restrict__ C, int M) {
  int wave = threadIdx.x >> 6;
  int lane = threadIdx.x & 63;
  int rt = blockIdx.x * 4 + wave;
  if (rt * 16 >= M) return;
  int kg = lane >> 4;
  int rloc = lane & 15;
  bf16x8 a[4];
  if constexpr (ABF) {
    const short* arow = (const short*)Ap + (size_t)(rt * 16 + rloc) * 128 + kg * 8;
#pragma unroll
    for (int kk = 0; kk < 4; kk++) a[kk] = *(const bf16x8*)(arow + kk * 32);
  } else {
    const float* arow = (const float*)Ap + (size_t)(rt * 16 + rloc) * 128 + kg * 8;
#pragma unroll
    for (int kk = 0; kk < 4; kk++) {
      float4 lo = *(const float4*)(arow + kk * 32);
      float4 hi = *(const float4*)(arow + kk * 32 + 4);
      bf16x8 tv;
      tv[0] = (short)f2bf(lo.x); tv[1] = (short)f2bf(lo.y);
      tv[2] = (short)f2bf(lo.z); tv[3] = (short)f2bf(lo.w);
      tv[4] = (short)f2bf(hi.x); tv[5] = (short)f2bf(hi.y);
      tv[6] = (short)f2bf(hi.z); tv[7] = (short)f2bf(hi.w);
      a[kk] = tv;
    }
  }
#pragma unroll
  for (int ct = 0; ct < 8; ct++) {
    f32x4 acc = {0.f, 0.f, 0.f, 0.f};
#pragma unroll
    for (int kk = 0; kk < 4; kk++) {
      bf16x8 bfr = *(const bf16x8*)(Wp + ((size_t)(ct * 4 + kk) * 64 + lane) * 8);
      acc = __builtin_amdgcn_mfma_f32_16x16x32_bf16(a[kk], bfr, acc, 0, 0, 0);
    }
    size_t cbase = (size_t)(rt * 16 + kg * 4) * 128 + ct * 16 + rloc;
#pragma unroll
    for (int j = 0; j < 4; j++) C[cbase + (size_t)j * 128] = (short)f2bf(acc[j]);
  }
}

// ---------------- gather: dst[t] = prelu(inv[t]*sum_{i in csr(t)} src[ids[i]] + bias) ----------------
// src bf16 rows (128 elems = 16 uint4); 16 lanes per target, 8 values per lane.
template <bool OBF>
__global__ __launch_bounds__(256) void gather_kernel(const uint4* __restrict__ src,
                                                     void* __restrict__ dst,
                                                     const int* __restrict__ off,
                                                     const int* __restrict__ ids,
                                                     const float* __restrict__ inv,
                                                     const float* __restrict__ bias,
                                                     const float* __restrict__ alpha_p, int T) {
  int tgt = blockIdx.x * 16 + (threadIdx.x >> 4);
  if (tgt >= T) return;
  int c = threadIdx.x & 15;
  int s = off[tgt], e = off[tgt + 1];
  float a0 = 0, a1 = 0, a2 = 0, a3 = 0, a4 = 0, a5 = 0, a6 = 0, a7 = 0;
  for (int i = s; i < e; i++) {
    int sid = ids[i];
    uint4 v = src[(size_t)sid * 16 + c];
    a0 += bfbits2f(v.x << 16); a1 += bfbits2f(v.x & 0xffff0000u);
    a2 += bfbits2f(v.y << 16); a3 += bfbits2f(v.y & 0xffff0000u);
    a4 += bfbits2f(v.z << 16); a5 += bfbits2f(v.z & 0xffff0000u);
    a6 += bfbits2f(v.w << 16); a7 += bfbits2f(v.w & 0xffff0000u);
  }
  float scv = inv[tgt];
  float al = *alpha_p;
  float b[8] = {0, 0, 0, 0, 0, 0, 0, 0};
  if (bias) {
    float4 b0 = ((const float4*)bias)[c * 2];
    float4 b1 = ((const float4*)bias)[c * 2 + 1];
    b[0] = b0.x; b[1] = b0.y; b[2] = b0.z; b[3] = b0.w;
    b[4] = b1.x; b[5] = b1.y; b[6] = b1.z; b[7] = b1.w;
  }
  float r[8] = {a0, a1, a2, a3, a4, a5, a6, a7};
#pragma unroll
  for (int j = 0; j < 8; j++) {
    float v = r[j] * scv + b[j];
    r[j] = (v >= 0.f) ? v : al * v;
  }
  if constexpr (OBF) {
    uint4 o;
    o.x = (f2bf(r[0]) & 0xffffu) | (f2bf(r[1]) << 16);
    o.y = (f2bf(r[2]) & 0xffffu) | (f2bf(r[3]) << 16);
    o.z = (f2bf(r[4]) & 0xffffu) | (f2bf(r[5]) << 16);
    o.w = (f2bf(r[6]) & 0xffffu) | (f2bf(r[7]) << 16);
    ((uint4*)dst)[(size_t)tgt * 16 + c] = o;
  } else {
    float4 o0; o0.x = r[0]; o0.y = r[1]; o0.z = r[2]; o0.w = r[3];
    float4 o1; o1.x = r[4]; o1.y = r[5]; o1.z = r[6]; o1.w = r[7];
    ((float4*)dst)[(size_t)tgt * 32 + c * 2] = o0;
    ((float4*)dst)[(size_t)tgt * 32 + c * 2 + 1] = o1;
  }
}

extern "C" void kernel_launch(void* const* d_in, const int* in_sizes, int n_in,
                              void* d_out, int out_size, void* d_ws, size_t ws_size,
                              hipStream_t stream) {
  const float* x = (const float*)d_in[0];
  const int* nidx = (const int*)d_in[1];
  int NI = in_sizes[1] / 2;
  const int* eidx = nidx + NI;
  const float* W0 = (const float*)d_in[2];
  const float* W1 = (const float*)d_in[3];
  const float* b0 = (const float*)d_in[4];
  const float* W2 = (const float*)d_in[5];
  const float* W3 = (const float*)d_in[6];
  const float* b1 = (const float*)d_in[7];
  const float* alpha = (const float*)d_in[8];

  char* ws = (char*)d_ws;
  size_t o = 0;
  auto alloc = [&](size_t bytes) { void* p = ws + o; o += (bytes + 255) & ~255ull; return p; };
  // persistent
  int* He = (int*)alloc((size_t)NBK * NBLK * 4);
  int* Hn = (int*)alloc((size_t)NBK * NBLK * 4);
  int* ebb = (int*)alloc((NBK + 1) * 4);
  int* nbb = (int*)alloc((NBK + 1) * 4);
  int* eoff = (int*)alloc((size_t)(NE + 1) * 4);
  int* noff = (int*)alloc((size_t)(NN + 1) * 4);
  float* einv = (float*)alloc((size_t)NE * 4);
  float* ninv = (float*)alloc((size_t)NN * 4);
  int* edge_nodes = (int*)alloc((size_t)NI * 4);
  int* node_edges = (int*)alloc((size_t)NI * 4);
  short* wp = (short*)alloc((size_t)4 * 16384 * 2);
  // arena: bin arrays (CSR build) alias activation buffers (compute phase)
  char* arena = (char*)alloc((size_t)NN * 128 * 2 * 2 + (size_t)NE * 128 * 2 * 2);
  int2* binE = (int2*)arena;
  int2* binN = (int2*)(arena + (size_t)NI * 8);
  short* bufNb = (short*)arena;                                  // NN x 128 bf16
  short* bufEb = (short*)(arena + (size_t)NN * 128 * 2);         // NE x 128 bf16
  short* n0b = (short*)(arena + (size_t)NN * 128 * 2 + (size_t)NE * 128 * 2);
  short* e0b = (short*)(arena + (size_t)NN * 128 * 4 + (size_t)NE * 128 * 2);

  float* outN = (float*)d_out;
  float* outE = outN + (size_t)NN * 128;

  // CSR build (both orientations)
  hist_kernel<<<NBLK, 256, 0, stream>>>(nidx, eidx, NI, He, Hn);
  scanH_kernel<<<2, 256, 0, stream>>>(He, Hn, ebb, nbb, NI);
  scatter_kernel<<<NBLK, 256, 0, stream>>>(nidx, eidx, NI, He, Hn, binE, binN);
  finalize_kernel<<<2 * NBK, 256, 0, stream>>>(binE, binN, ebb, nbb, eoff, noff,
                                               einv, ninv, edge_nodes, node_edges, NI);
  packw_kernel<<<256, 256, 0, stream>>>(W0, W1, W2, W3, wp);

  int gN = (NN / 16 + 3) / 4, gE = (NE / 16 + 3) / 4;
  // layer 0
  gemm_kernel<false><<<gN, 256, 0, stream>>>(x, wp + 0 * 16384, bufNb, NN);
  gather_kernel<true><<<(NE + 15) / 16, 256, 0, stream>>>((const uint4*)bufNb, e0b,
                                                          eoff, edge_nodes, einv, nullptr, alpha, NE);
  gemm_kernel<true><<<gE, 256, 0, stream>>>(e0b, wp + 1 * 16384, bufEb, NE);
  gather_kernel<true><<<(NN + 15) / 16, 256, 0, stream>>>((const uint4*)bufEb, n0b,
                                                          noff, node_edges, ninv, b0, alpha, NN);
  // layer 1
  gemm_kernel<true><<<gN, 256, 0, stream>>>(n0b, wp + 2 * 16384, bufNb, NN);
  gather_kernel<false><<<(NE + 15) / 16, 256, 0, stream>>>((const uint4*)bufNb, outE,
                                                           eoff, edge_nodes, einv, nullptr, alpha, NE);
  gemm_kernel<false><<<gE, 256, 0, stream>>>(outE, wp + 3 * 16384, bufEb, NE);
  gather_kernel<true><<<1, 1, 0, stream>>>((const uint4*)bufEb, e0b, eoff, edge_nodes,
                                           einv, nullptr, alpha, 0);  // no-op keep symbols
  gather_kernel<false><<<(NN + 15) / 16, 256, 0, stream>>>((const uint4*)bufEb, outN,
                                                           noff, node_edges, ninv, b1, alpha, NN);
}